// Round 8
// baseline (49.504 us; speedup 1.0000x reference)
//
#include <hip/hip_runtime.h>
#include <math.h>

// Problem constants (from setup_inputs)
#define NG    1000   // num_graphs
#define NPG   128    // nodes_per_graph
#define FF    59     // features
#define D1    128    // hidden 1
#define D2    256    // hidden 2
#define EPSV  1e-5f

// NOTE on the neighbor graph: the reference's  d2 + eye(n)*inf  makes every
// OFF-diagonal entry 0*inf = NaN (diag = +inf); top_k(-d2) then selects,
// stably, the 3 lowest indices != i:
//   idx[i] = {0,1,2} for i>=3;  {1,2,3}, {0,2,3}, {0,1,3} for i=0,1,2.
// So v_j = x_j @ w1b is only needed for j in {0,1,2,3}, and
//   sum_edges relu(u_i + v_j) = sum_i S3(i) + sum_{i<3} [relu(u_i+v3) - relu(u_i+v_i)]
// where S3(i) = relu(u_i+v0)+relu(u_i+v1)+relu(u_i+v2),
//       u_i = x_i @ (w1a - w1b) + b1   (b1 folded into wu's k=59 row, x pad=1.0)
//
// Round-8 structure: 1-wave blocks (64 thr), 4 blocks per graph (32 rows each),
// zero LDS / zero barriers in main; vv computed redundantly per block via a
// third MFMA tile and broadcast with __shfl; quarter partials -> ws, head sums.

typedef short  short8  __attribute__((ext_vector_type(8)));
typedef float  f32x4   __attribute__((ext_vector_type(4)));

// ws layout (bytes): [0,16384) wu blob; [16384,32768) wb blob;
// [32768, 32768+2048000) x2part: [1000][4][128] f32 raw quarter sums
#define WS_WB_SHORTS 8192
#define WS_X2_OFF    32768

static __device__ __forceinline__ unsigned short f2bf(float f) {
    union { float f; unsigned u; } v; v.f = f;
    unsigned r = v.u + 0x7FFFu + ((v.u >> 16) & 1u);   // RNE
    return (unsigned short)(r >> 16);
}

// ---------------------------------------------------------------------------
// Kernel B: build wu blob (blocks 0..15) and wb blob (blocks 16..31).
// frag (s,nt) at ((s*8+nt)*64 + lane)*8 shorts; lane gives d = nt*16+(l&15),
// k0 = s*32+(l>>4)*8 — exactly the MFMA B-fragment each lane needs.
// ---------------------------------------------------------------------------
__global__ __launch_bounds__(64) void ecn_blob(
    const float* __restrict__ w1, const float* __restrict__ b1,
    short* __restrict__ blob)
{
    const int bid = blockIdx.x;
    const int l = threadIdx.x;
    const bool isB = (bid >= 16);
    const int fid = isB ? (bid - 16) : bid;
    const int s = fid >> 3, nt = fid & 7;
    const int lr = l & 15, lg = l >> 4;
    const int d = nt * 16 + lr, k0 = s * 32 + lg * 8;
    short8 pk;
    #pragma unroll
    for (int j = 0; j < 8; ++j) {
        int k = k0 + j;
        float v = 0.0f;
        if (k < FF) {
            float wb_ = w1[(size_t)(FF + k) * D1 + d];
            v = isB ? wb_ : (w1[(size_t)k * D1 + d] - wb_);
        } else if (k == FF && !isB) {
            v = b1[d];                       // bias row only in wu
        }
        pk[j] = (short)f2bf(v);
    }
    *(short8*)&blob[(size_t)(isB ? WS_WB_SHORTS : 0) + ((s * 8 + nt) * 64 + l) * 8] = pk;
}

// ---------------------------------------------------------------------------
// Kernel M: one wave per quarter-graph. No LDS, no barriers.
// ---------------------------------------------------------------------------
__global__ __launch_bounds__(64, 2) void ecn_main(
    const float* __restrict__ x, const short* __restrict__ blob,
    float* __restrict__ x2p)
{
    const int blk = blockIdx.x;          // 0..3999
    const int g = blk >> 2, qtr = blk & 3;
    const int l = threadIdx.x;           // 0..63
    const int lr = l & 15, lg = l >> 4;

    const float* xg = x + (size_t)g * NPG * FF;
    const int i0 = qtr * 32 + lr;        // mt=0 row
    const int i1 = i0 + 16;              // mt=1 row
    const short8* wu8 = (const short8*)blob;
    const short8* wb8 = (const short8*)(blob + WS_WB_SHORTS);

    // ---- A fragments for rows i0, i1 and (vv) rows lr, both k-steps ----
    short8 a0[2], a1[2], av[2];
    #pragma unroll
    for (int s = 0; s < 2; ++s) {
        float xv0[8], xv1[8], xvv[8];
        if (s == 0) {
            const float* p0 = xg + i0 * FF + lg * 8;
            const float* p1 = xg + i1 * FF + lg * 8;
            const float* pv = xg + lr * FF + lg * 8;
            #pragma unroll
            for (int j = 0; j < 8; ++j) {
                xv0[j] = p0[j]; xv1[j] = p1[j];
                xvv[j] = (qtr == 0) ? xv0[j] : pv[j];
            }
        } else {
            #pragma unroll
            for (int j = 0; j < 8; ++j) {
                int k = 32 + lg * 8 + j;              // lane-varying
                bool valid = (k < FF);
                float pad = (k == FF) ? 1.0f : 0.0f;  // b1 row at k=59 (wu only)
                int o0 = valid ? (i0 * FF + k) : 0;
                int o1 = valid ? (i1 * FF + k) : 0;
                int ov = valid ? (lr * FF + k) : 0;
                float t0 = xg[o0], t1 = xg[o1], tv = xg[ov];
                xv0[j] = valid ? t0 : pad;
                xv1[j] = valid ? t1 : pad;
                xvv[j] = (qtr == 0) ? xv0[j] : (valid ? tv : pad);
            }
        }
        #pragma unroll
        for (int j = 0; j < 8; ++j) {
            a0[s][j] = (short)f2bf(xv0[j]);
            a1[s][j] = (short)f2bf(xv1[j]);
            av[s][j] = (short)f2bf(xvv[j]);
        }
    }

    // ---- MFMA: u tiles (2) + vv tile (1), 48 independent chains ----
    f32x4 acc0[8], acc1[8], accv[8];
    #pragma unroll
    for (int nt = 0; nt < 8; ++nt) {
        acc0[nt] = (f32x4)0.0f; acc1[nt] = (f32x4)0.0f; accv[nt] = (f32x4)0.0f;
    }
    #pragma unroll
    for (int s = 0; s < 2; ++s) {
        #pragma unroll
        for (int nt = 0; nt < 8; ++nt) {
            short8 b = wu8[(s * 8 + nt) * 64 + l];
            acc0[nt] = __builtin_amdgcn_mfma_f32_16x16x32_bf16(a0[s], b, acc0[nt], 0, 0, 0);
            acc1[nt] = __builtin_amdgcn_mfma_f32_16x16x32_bf16(a1[s], b, acc1[nt], 0, 0, 0);
            short8 bb = wb8[(s * 8 + nt) * 64 + l];
            accv[nt] = __builtin_amdgcn_mfma_f32_16x16x32_bf16(av[s], bb, accv[nt], 0, 0, 0);
        }
    }

    // ---- epilogue: vv broadcast via shfl; relu-edge partial sums ----
    // C/D: col = lane&15, row = (lane>>4)*4+q. vv rows 0..3 live in lanes 0..15.
    float part[8];
    #pragma unroll
    for (int nt = 0; nt < 8; ++nt) {
        const float v0 = __shfl(accv[nt][0], lr);
        const float v1_ = __shfl(accv[nt][1], lr);
        const float v2_ = __shfl(accv[nt][2], lr);
        const float v3_ = __shfl(accv[nt][3], lr);
        float s = 0.0f;
        #pragma unroll
        for (int q = 0; q < 4; ++q) {
            float u = acc0[nt][q];
            s += fmaxf(u + v0, 0.0f) + fmaxf(u + v1_, 0.0f) + fmaxf(u + v2_, 0.0f);
            u = acc1[nt][q];
            s += fmaxf(u + v0, 0.0f) + fmaxf(u + v1_, 0.0f) + fmaxf(u + v2_, 0.0f);
        }
        if (qtr == 0 && lg == 0) {         // global rows 0,1,2 (mt=0, q=0..2)
            float u0 = acc0[nt][0], u1 = acc0[nt][1], u2 = acc0[nt][2];
            s += fmaxf(u0 + v3_, 0.0f) - fmaxf(u0 + v0,  0.0f);
            s += fmaxf(u1 + v3_, 0.0f) - fmaxf(u1 + v1_, 0.0f);
            s += fmaxf(u2 + v3_, 0.0f) - fmaxf(u2 + v2_, 0.0f);
        }
        s += __shfl_xor(s, 16);
        s += __shfl_xor(s, 32);
        part[nt] = s;
    }
    if (lg == 0) {                          // lanes 0..15 write 8 dims each
        float* dst = x2p + (size_t)blk * D1;
        #pragma unroll
        for (int nt = 0; nt < 8; ++nt) dst[nt * 16 + lr] = part[nt];
    }
}

// ---------------------------------------------------------------------------
// Kernel H: sum quarter partials + BN1, then batched head MLP (4 graphs/block)
// ---------------------------------------------------------------------------
__global__ __launch_bounds__(256) void ecn_head(
    const float* __restrict__ x2p,
    const float* __restrict__ g1, const float* __restrict__ be1,
    const float* __restrict__ m1, const float* __restrict__ v1,
    const float* __restrict__ w2, const float* __restrict__ b2,
    const float* __restrict__ g2, const float* __restrict__ be2,
    const float* __restrict__ m2, const float* __restrict__ v2,
    const float* __restrict__ w3, const float* __restrict__ b3,
    const float* __restrict__ g3, const float* __restrict__ be3,
    const float* __restrict__ m3, const float* __restrict__ v3,
    float* __restrict__ out)
{
    const int t = threadIdx.x;
    const int gbase = blockIdx.x * 4;
    __shared__ float xt[4][D1];     // 2 KB
    __shared__ float part[4][4];

    #pragma unroll
    for (int k = 0; k < 2; ++k) {
        int idx = t + k * 256;              // 0..511
        int gi = idx >> 7, f = idx & 127;
        const float* p = x2p + ((size_t)(gbase + gi) * 4) * D1 + f;
        float raw = p[0] + p[D1] + p[2 * D1] + p[3 * D1];
        float sc = g1[f] * rsqrtf(v1[f] + EPSV);
        xt[gi][f] = sc * (raw * (1.0f / (3 * NPG))) + (be1[f] - m1[f] * sc);
    }
    __syncthreads();

    const int d = t;
    float h[4];
    #pragma unroll
    for (int gi = 0; gi < 4; ++gi) h[gi] = b2[d];
    #pragma unroll 16
    for (int f = 0; f < D1; ++f) {
        float wv = w2[(size_t)f * D2 + d];
        #pragma unroll
        for (int gi = 0; gi < 4; ++gi) h[gi] = fmaf(xt[gi][f], wv, h[gi]);
    }
    const float sc2 = g2[d] * rsqrtf(v2[d] + EPSV);
    const float sh2 = be2[d] - m2[d] * sc2;
    const float w3d = w3[d];
    #pragma unroll
    for (int gi = 0; gi < 4; ++gi) {
        float r = (sc2 * fmaxf(h[gi], 0.0f) + sh2) * w3d;
        #pragma unroll
        for (int off = 32; off > 0; off >>= 1) r += __shfl_down(r, off);
        if ((t & 63) == 0) part[t >> 6][gi] = r;
    }
    __syncthreads();
    if (t < 4) {
        float s = part[0][t] + part[1][t] + part[2][t] + part[3][t] + b3[0];
        s = fmaxf(s, 0.0f);
        float sc3 = g3[0] * rsqrtf(v3[0] + EPSV);
        s = sc3 * s + (be3[0] - m3[0] * sc3);
        out[gbase + t] = 1.0f / (1.0f + expf(-s));
    }
}

extern "C" void kernel_launch(void* const* d_in, const int* in_sizes, int n_in,
                              void* d_out, int out_size, void* d_ws, size_t ws_size,
                              hipStream_t stream) {
    const float* x   = (const float*)d_in[0];
    // d_in[1] = pos — unused: the reference's knn degenerates (see NOTE)
    const float* w1  = (const float*)d_in[2];
    const float* b1  = (const float*)d_in[3];
    const float* g1  = (const float*)d_in[4];
    const float* be1 = (const float*)d_in[5];
    const float* m1  = (const float*)d_in[6];
    const float* v1  = (const float*)d_in[7];
    const float* w2  = (const float*)d_in[8];
    const float* b2  = (const float*)d_in[9];
    const float* g2  = (const float*)d_in[10];
    const float* be2 = (const float*)d_in[11];
    const float* m2  = (const float*)d_in[12];
    const float* v2  = (const float*)d_in[13];
    const float* w3  = (const float*)d_in[14];
    const float* b3  = (const float*)d_in[15];
    const float* g3  = (const float*)d_in[16];
    const float* be3 = (const float*)d_in[17];
    const float* m3  = (const float*)d_in[18];
    const float* v3  = (const float*)d_in[19];
    float* outp = (float*)d_out;

    short* blob = (short*)d_ws;
    float* x2p  = (float*)((char*)d_ws + WS_X2_OFF);

    ecn_blob<<<32, 64, 0, stream>>>(w1, b1, blob);
    ecn_main<<<4 * NG, 64, 0, stream>>>(x, blob, x2p);
    ecn_head<<<NG / 4, 256, 0, stream>>>(x2p, g1, be1, m1, v1,
                                         w2, b2, g2, be2, m2, v2,
                                         w3, b3, g3, be3, m3, v3, outp);
}

// Round 9
// 26.996 us; speedup vs baseline: 1.8338x; 1.8338x over previous
//
#include <hip/hip_runtime.h>
#include <math.h>

// Problem constants (from setup_inputs)
#define NG    1000   // num_graphs
#define NPG   128    // nodes_per_graph
#define FF    59     // features
#define D1    128    // hidden 1
#define D2    256    // hidden 2
#define EPSV  1e-5f

// NOTE on the neighbor graph: the reference's  d2 + eye(n)*inf  makes every
// OFF-diagonal entry 0*inf = NaN (diag = +inf); top_k(-d2) then selects,
// stably, the 3 lowest indices != i:
//   idx[i] = {0,1,2} for i>=3;  {1,2,3}, {0,2,3}, {0,1,3} for i=0,1,2.
// So v_j = x_j @ w1b is only needed for j in {0,1,2,3}, and
//   sum_edges relu(u_i + v_j) = sum_i S3(i) + sum_{i<3} [relu(u_i+v3) - relu(u_i+v_i)]
// where S3(i) = relu(u_i+v0)+relu(u_i+v1)+relu(u_i+v2),
//       u_i = x_i @ (w1a - w1b) + b1   (b1 folded into wu's k=59 row, x pad=1.0)
//
// Round-9 structure: R6's best-known main (direct-global A-fragments, prep'd
// wu blob + per-graph vv in ws) with the head MLP fused back into the
// per-graph block (head is per-graph independent; w2 dedup proved worthless
// in R5). 2 kernels total, no x2 round-trip, no head launch.

typedef short  short8  __attribute__((ext_vector_type(8)));
typedef float  f32x4   __attribute__((ext_vector_type(4)));

// ws layout (bytes): [0,16384) wu blob (bf16 frag-ordered);
// [16384, 16384+2048000) vv_all: [1000][4][128] f32
#define WS_VV_OFF  16384

static __device__ __forceinline__ unsigned short f2bf(float f) {
    union { float f; unsigned u; } v; v.f = f;
    unsigned r = v.u + 0x7FFFu + ((v.u >> 16) & 1u);   // RNE
    return (unsigned short)(r >> 16);
}

// ---------------------------------------------------------------------------
// Kernel P: build wu fragment blob (blocks 0..15) + vv for every graph (16..1015)
// blob layout: frag (s,nt) at ((s*8+nt)*64 + lane)*8 shorts; lane gives
// d = nt*16+(l&15), k0 = s*32+(l>>4)*8 — exactly the MFMA B-fragment each lane needs.
// ---------------------------------------------------------------------------
__global__ __launch_bounds__(256) void ecn_prep(
    const float* __restrict__ x, const float* __restrict__ w1,
    const float* __restrict__ b1, short* __restrict__ blob,
    float* __restrict__ vvws)
{
    const int bid = blockIdx.x;
    if (bid < 16) {
        const int l = threadIdx.x;
        if (l >= 64) return;
        const int s = bid >> 3, nt = bid & 7;
        const int lr = l & 15, lg = l >> 4;
        const int d = nt * 16 + lr, k0 = s * 32 + lg * 8;
        short8 pk;
        #pragma unroll
        for (int j = 0; j < 8; ++j) {
            int k = k0 + j;
            float v = 0.0f;
            if (k < FF)       v = w1[(size_t)k * D1 + d] - w1[(size_t)(FF + k) * D1 + d];
            else if (k == FF) v = b1[d];
            pk[j] = (short)f2bf(v);
        }
        *(short8*)&blob[((s * 8 + nt) * 64 + l) * 8] = pk;
    } else {
        const int g = bid - 16;
        const int t = threadIdx.x;
        const int d = t & 127, p = t >> 7;
        const float* xg = x + (size_t)g * NPG * FF;
        const float* r0 = xg + (p * 2) * FF;
        const float* r1 = r0 + FF;
        float a0 = 0.0f, a1 = 0.0f;
        for (int f = 0; f < FF; ++f) {
            float wv = w1[(size_t)(FF + f) * D1 + d];
            a0 = fmaf(r0[f], wv, a0);
            a1 = fmaf(r1[f], wv, a1);
        }
        vvws[(size_t)g * 512 + (p * 2) * 128 + d] = a0;
        vvws[(size_t)g * 512 + (p * 2 + 1) * 128 + d] = a1;
    }
}

// ---------------------------------------------------------------------------
// Kernel F: per-graph MFMA u-GEMM + fused relu-edge aggregation + BN1 + head
// MLP + sigmoid -> out[g]. A-fragments loaded directly from global x.
// ---------------------------------------------------------------------------
__global__ __launch_bounds__(256, 4) void ecn_fused(
    const float* __restrict__ x, const short* __restrict__ blob,
    const float* __restrict__ vvws,
    const float* __restrict__ g1, const float* __restrict__ be1,
    const float* __restrict__ m1, const float* __restrict__ v1,
    const float* __restrict__ w2, const float* __restrict__ b2,
    const float* __restrict__ g2, const float* __restrict__ be2,
    const float* __restrict__ m2, const float* __restrict__ v2,
    const float* __restrict__ w3, const float* __restrict__ b3,
    const float* __restrict__ g3, const float* __restrict__ be3,
    const float* __restrict__ m3, const float* __restrict__ v3,
    float* __restrict__ out)
{
    const int g = blockIdx.x;
    const int t = threadIdx.x;

    __shared__ float vvsh[4 * D1];   // 2 KB
    __shared__ float Sp[4][D1];      // 2 KB
    __shared__ float x2s[D1];        // 512 B
    __shared__ float rpart[4];

    const float* xg = x + (size_t)g * NPG * FF;

    // vv copy (512 f32, coalesced float4, L2-hot)
    if (t < 128) {
        ((float4*)vvsh)[t] = ((const float4*)(vvws + (size_t)g * 512))[t];
    }

    const int wave = t >> 6, l = t & 63;
    const int lr = l & 15, lg = l >> 4;
    const int i0 = wave * 32 + lr;        // mt=0 row
    const int i1 = i0 + 16;               // mt=1 row
    const short8* blob8 = (const short8*)blob;

    f32x4 acc[2][8];
    #pragma unroll
    for (int mt = 0; mt < 2; ++mt)
        #pragma unroll
        for (int nt = 0; nt < 8; ++nt) acc[mt][nt] = (f32x4)0.0f;

    #pragma unroll
    for (int s = 0; s < 2; ++s) {
        // ---- A fragments: 8 consecutive floats of rows i0/i1 at k0 = s*32+lg*8 ----
        float xv0[8], xv1[8];
        if (s == 0) {
            const float* p0 = xg + i0 * FF + lg * 8;
            const float* p1 = xg + i1 * FF + lg * 8;
            #pragma unroll
            for (int j = 0; j < 8; ++j) { xv0[j] = p0[j]; xv1[j] = p1[j]; }
        } else {
            #pragma unroll
            for (int j = 0; j < 8; ++j) {
                int k = 32 + lg * 8 + j;          // lane-varying
                bool valid = (k < FF);
                int o0 = valid ? (i0 * FF + k) : 0;
                int o1 = valid ? (i1 * FF + k) : 0;
                float pad = (k == FF) ? 1.0f : 0.0f;   // b1 row at k=59
                float t0 = xg[o0], t1 = xg[o1];
                xv0[j] = valid ? t0 : pad;
                xv1[j] = valid ? t1 : pad;
            }
        }
        short8 a0, a1;
        #pragma unroll
        for (int j = 0; j < 8; ++j) {
            a0[j] = (short)f2bf(xv0[j]);
            a1[j] = (short)f2bf(xv1[j]);
        }
        // ---- B fragments from L2-hot blob (lane-coalesced dwordx4) + MFMA ----
        #pragma unroll
        for (int nt = 0; nt < 8; ++nt) {
            short8 b = blob8[(s * 8 + nt) * 64 + l];
            acc[0][nt] = __builtin_amdgcn_mfma_f32_16x16x32_bf16(a0, b, acc[0][nt], 0, 0, 0);
            acc[1][nt] = __builtin_amdgcn_mfma_f32_16x16x32_bf16(a1, b, acc[1][nt], 0, 0, 0);
        }
    }
    __syncthreads();   // vvsh visible

    // epilogue: C/D col=lane&15, row=(lane>>4)*4+q; global row = wave*32+mt*16+lg*4+q
    #pragma unroll
    for (int nt = 0; nt < 8; ++nt) {
        const int d = nt * 16 + lr;
        const float v0 = vvsh[d], v1_ = vvsh[128 + d], v2_ = vvsh[256 + d], v3_ = vvsh[384 + d];
        float s = 0.0f;
        #pragma unroll
        for (int mt = 0; mt < 2; ++mt)
            #pragma unroll
            for (int q = 0; q < 4; ++q) {
                float u = acc[mt][nt][q];   // b1 already inside via k=59 row
                s += fmaxf(u + v0, 0.0f) + fmaxf(u + v1_, 0.0f) + fmaxf(u + v2_, 0.0f);
            }
        if (wave == 0 && lg == 0) {         // global rows 0,1,2
            float u0 = acc[0][nt][0], u1 = acc[0][nt][1], u2 = acc[0][nt][2];
            s += fmaxf(u0 + v3_, 0.0f) - fmaxf(u0 + v0,  0.0f);
            s += fmaxf(u1 + v3_, 0.0f) - fmaxf(u1 + v1_, 0.0f);
            s += fmaxf(u2 + v3_, 0.0f) - fmaxf(u2 + v2_, 0.0f);
        }
        s += __shfl_xor(s, 16);
        s += __shfl_xor(s, 32);
        if (lg == 0) Sp[wave][d] = s;
    }
    __syncthreads();

    // BN1 (affine commutes with the means) -> x2 in LDS
    if (t < D1) {
        float tot = Sp[0][t] + Sp[1][t] + Sp[2][t] + Sp[3][t];
        float sc = g1[t] * rsqrtf(v1[t] + EPSV);
        x2s[t] = sc * (tot * (1.0f / (3 * NPG))) + (be1[t] - m1[t] * sc);
    }
    __syncthreads();

    // head MLP: h2 = bn2(relu(x2@w2+b2)); h3 = bn3(relu(h2@w3+b3)); sigmoid
    {
        float h = b2[t];
        #pragma unroll 16
        for (int f = 0; f < D1; ++f)
            h = fmaf(x2s[f], w2[(size_t)f * D2 + t], h);
        h = fmaxf(h, 0.0f);
        float sc2 = g2[t] * rsqrtf(v2[t] + EPSV);
        h = sc2 * h + (be2[t] - m2[t] * sc2);
        float r = h * w3[t];
        #pragma unroll
        for (int off = 32; off > 0; off >>= 1) r += __shfl_down(r, off);
        if ((t & 63) == 0) rpart[t >> 6] = r;
    }
    __syncthreads();
    if (t == 0) {
        float s = rpart[0] + rpart[1] + rpart[2] + rpart[3] + b3[0];
        s = fmaxf(s, 0.0f);
        float sc3 = g3[0] * rsqrtf(v3[0] + EPSV);
        s = sc3 * s + (be3[0] - m3[0] * sc3);
        out[g] = 1.0f / (1.0f + expf(-s));
    }
}

extern "C" void kernel_launch(void* const* d_in, const int* in_sizes, int n_in,
                              void* d_out, int out_size, void* d_ws, size_t ws_size,
                              hipStream_t stream) {
    const float* x   = (const float*)d_in[0];
    // d_in[1] = pos — unused: the reference's knn degenerates (see NOTE)
    const float* w1  = (const float*)d_in[2];
    const float* b1  = (const float*)d_in[3];
    const float* g1  = (const float*)d_in[4];
    const float* be1 = (const float*)d_in[5];
    const float* m1  = (const float*)d_in[6];
    const float* v1  = (const float*)d_in[7];
    const float* w2  = (const float*)d_in[8];
    const float* b2  = (const float*)d_in[9];
    const float* g2  = (const float*)d_in[10];
    const float* be2 = (const float*)d_in[11];
    const float* m2  = (const float*)d_in[12];
    const float* v2  = (const float*)d_in[13];
    const float* w3  = (const float*)d_in[14];
    const float* b3  = (const float*)d_in[15];
    const float* g3  = (const float*)d_in[16];
    const float* be3 = (const float*)d_in[17];
    const float* m3  = (const float*)d_in[18];
    const float* v3  = (const float*)d_in[19];
    float* outp = (float*)d_out;

    short* blob = (short*)d_ws;
    float* vvws = (float*)((char*)d_ws + WS_VV_OFF);

    ecn_prep<<<16 + NG, 256, 0, stream>>>(x, w1, b1, blob, vvws);
    ecn_fused<<<NG, 256, 0, stream>>>(x, blob, vvws, g1, be1, m1, v1,
                                      w2, b2, g2, be2, m2, v2,
                                      w3, b3, g3, be3, m3, v3, outp);
}